// Round 9
// baseline (74.295 us; speedup 1.0000x reference)
//
#include <hip/hip_runtime.h>
#include <math.h>

#define IMG_W 112
#define HW    12544          // 112*112
#define CI    8
#define CO    16
#define NP    72             // patch positions
#define EPS   1e-6f

typedef __attribute__((ext_vector_type(8))) short short8;  // 8 bf16 = 4 VGPRs
typedef __attribute__((ext_vector_type(4))) float f32x4;

static __device__ inline short f2bf(float f) {  // RNE float->bf16 bits
  unsigned u = __float_as_uint(f);
  return (short)((u + 0x7FFFu + ((u >> 16) & 1u)) >> 16);
}

static constexpr int DQ[9] = {-113, -112, -111, -1, 0, 1, 111, 112, 113};

// Round 9: occupancy push. LDS cut 46.2KB -> 32.4KB so 4 blocks/CU resident
// (= 32 waves/CU hardware max; round 8's 3 blocks/CU left a serialized 4th
// round on 16 CUs). Changes vs r8:
//  - sA stores ONLY quad-0 weight fragments (1152 rows x 8 bf16, 18.4KB).
//    A-quads 1..3 read a shared 16B zero row via address cndmask (K slots
//    8..31 contribute nothing).
//  - bias dropped from K: added in the fold from an fp32 table, float4 per
//    (p, quad) = bias[p][quad*4..+3] (16-lane broadcast, conflict-free):
//    t = d + bq; acc += pv*t; n2 += t*t.  (fp32 bias add: accuracy >= r8)
//  - B-frag: quad0 = x[c,n] bf16, quads 1..3 = 0 (no 1.0 row needed).
// Wave = (half, group): group owns 16 pixels, half owns 4 channels (36 p's).
__global__ __launch_bounds__(512) void coda_mfma(
    const float* __restrict__ in, const float* __restrict__ wp,
    const float* __restrict__ bp, float* __restrict__ out)
{
  __shared__ short8 sA[NP * 16];    // 18432B: [p*16+m] = 8 bf16 weights
  __shared__ float  sBiasF[NP * 16];//  4608B: fp32 bias, row o = p*16+co
  __shared__ float  sBuf[CI * 290]; //  9280B: input stage, then partials
  __shared__ short8 sZero[1];       //    16B zero A-row for quads 1..3

  const int tid = threadIdx.x;
  const int b   = blockIdx.x / 196;            // 196 blocks (64 px) per image
  const int r0  = (blockIdx.x - b * 196) * 64; // first flat pixel of block
  const float* __restrict__ inb = in + b * CI * HW;

  // ---- stage A rows (bf16) ----
  for (int i = tid; i < NP * 16; i += 512) {
    const float* wr = wp + i * CI;
    short8 v;
#pragma unroll
    for (int j = 0; j < 8; ++j) v[j] = f2bf(wr[j]);
    sA[i] = v;
  }
  // ---- stage fp32 bias ----
  {
    const float4* __restrict__ b4 = (const float4*)bp;
    float4* s4 = (float4*)sBiasF;
    for (int i = tid; i < NP * 4; i += 512) s4[i] = b4[i];
  }
  if (tid == 0) { short8 z = {0,0,0,0,0,0,0,0}; sZero[0] = z; }
  // ---- stage input neighborhood: flat offsets [r0-113, r0+176] clamped ----
  for (int k = tid; k < CI * 290; k += 512) {
    const int c = k / 290;
    const int i = k - c * 290;
    int gg = r0 - 113 + i;
    gg = (gg < 0) ? 0 : (gg > HW - 1 ? HW - 1 : gg);
    sBuf[k] = inb[c * HW + gg];
  }
  __syncthreads();

  const int wave = tid >> 6;
  const int lane = tid & 63;
  const int g    = wave & 3;                   // pixel group
  const int half = wave >> 2;                  // channel half
  const int ln   = lane & 15;                  // pixel slot = A row m = B col n
  const int quad = lane >> 4;
  const int rwav = r0 + g * 16;
  const int h    = rwav / IMG_W;
  const int wl   = (rwav - h * IMG_W) + ln;    // this lane's pixel column
  const int off  = g * 16 + ln + 113;          // center index into sBuf rows

  // border masks per q = kh*3+kw
  float vm[9];
#pragma unroll
  for (int q = 0; q < 9; ++q) {
    const int kh = q / 3, kw = q % 3;
    const bool ok = ((unsigned)(h + kh - 1) < 112u) &&
                    ((unsigned)(wl + kw - 1) < 112u);
    vm[q] = ok ? 1.f : 0.f;
  }

  // B fragment: quad0 = x[c,n] bf16 (8 channels); quads 1..3 = 0
  short8 bf = {0, 0, 0, 0, 0, 0, 0, 0};
  if (quad == 0) {
#pragma unroll
    for (int j = 0; j < 8; ++j) bf[j] = f2bf(sBuf[j * 290 + off]);
  }

  float acc[4] = {0.f, 0.f, 0.f, 0.f};
  float n2[4]  = {0.f, 0.f, 0.f, 0.f};
  const int c0 = half * 4;

#pragma unroll 1
  for (int cc = 0; cc < 4; ++cc) {
    const int c = c0 + cc;
    const float* __restrict__ sc = &sBuf[c * 290 + off];
#pragma unroll
    for (int q = 0; q < 9; ++q) {
      const int p = c * 9 + q;
      const short8* ap = (quad == 0) ? &sA[(p << 4) + ln] : &sZero[0];
      const short8 af = *ap;
      const f32x4 bq = *(const f32x4*)&sBiasF[(p << 4) + (quad << 2)];
      const float pv = vm[q] * sc[DQ[q]];
      const f32x4 zc = {0.f, 0.f, 0.f, 0.f};
      const f32x4 d = __builtin_amdgcn_mfma_f32_16x16x32_bf16(af, bf, zc, 0, 0, 0);
#pragma unroll
      for (int i = 0; i < 4; ++i) {
        const float t = d[i] + bq[i];        // raw = W·x + b (fp32 bias)
        acc[i] = fmaf(pv, t, acc[i]);
        n2[i]  = fmaf(t, t, n2[i]);
      }
    }
  }

  // ---- combine halves via LDS (sBuf is dead now), half 0 stores ----
  __syncthreads();
  if (half == 1) {
#pragma unroll
    for (int i = 0; i < 4; ++i) {
      sBuf[i * 256 + g * 64 + lane]       = acc[i];   // conflict-free b32
      sBuf[(i + 4) * 256 + g * 64 + lane] = n2[i];
    }
  }
  __syncthreads();
  if (half == 0) {
    float* __restrict__ ob = out + (long)b * CO * HW + rwav + ln;
#pragma unroll
    for (int i = 0; i < 4; ++i) {
      const float a2 = acc[i] + sBuf[i * 256 + g * 64 + lane];
      const float s2 = n2[i] + sBuf[(i + 4) * 256 + g * 64 + lane];
      const int co = quad * 4 + i;                    // C/D row = quad*4+reg
      ob[(long)co * HW] = a2 / (sqrtf(s2) + EPS);
    }
  }
}

extern "C" void kernel_launch(void* const* d_in, const int* in_sizes, int n_in,
                              void* d_out, int out_size, void* d_ws, size_t ws_size,
                              hipStream_t stream) {
  const float* in = (const float*)d_in[0];
  const float* wp = (const float*)d_in[1];
  const float* bp = (const float*)d_in[2];
  float* out = (float*)d_out;

  // 50176 pixels / 64 per block = 784 blocks of 8 waves (p-split pairs)
  coda_mfma<<<dim3(784), dim3(512), 0, stream>>>(in, wp, bp, out);
}

// Round 10
// 73.814 us; speedup vs baseline: 1.0065x; 1.0065x over previous
//
#include <hip/hip_runtime.h>
#include <math.h>

#define IMG_W 112
#define HW    12544          // 112*112
#define CI    8
#define CO    16
#define NP    72             // patch positions
#define EPS   1e-6f

typedef __attribute__((ext_vector_type(8))) short short8;  // 8 bf16 = 4 VGPRs
typedef __attribute__((ext_vector_type(4))) float f32x4;
typedef __attribute__((ext_vector_type(2))) float f32x2;

static __device__ inline short f2bf(float f) {  // RNE float->bf16 bits
  unsigned u = __float_as_uint(f);
  return (short)((u + 0x7FFFu + ((u >> 16) & 1u)) >> 16);
}

static constexpr int DQ[9] = {-113, -112, -111, -1, 0, 1, 111, 112, 113};

// Round 10 = round 8 structure (bias-in-K, 46KB LDS, 6272 waves) with:
//  1. __launch_bounds__(512,4): cap VGPR at 128 -> 4 waves/SIMD resident.
//     (r8's full 36-MFMA unroll likely hoisted ~36 A-frags -> >170 VGPR ->
//      2-3 waves/SIMD; LDS tweaks in r9 couldn't fix a register cap.)
//  2. unroll 2 on the channel loop: 18-MFMA scheduling windows fit the cap.
//  3. Packed folds: acc/n2 as f32x2 via __builtin_elementwise_fma ->
//     v_pk_fma_f32, halving the per-p fold VALU (8 -> 4 insts).
__global__ __launch_bounds__(512, 4) void coda_mfma(
    const float* __restrict__ in, const float* __restrict__ wp,
    const float* __restrict__ bp, float* __restrict__ out)
{
  __shared__ short sA[NP][32][8];   // 36864B, A-frag order: [p][quad*16+m][j]
  __shared__ float sBuf[CI * 290];  //  9280B: input stage, then partials
  __shared__ short sZ[16];          //    32B zero frag for quads 2,3

  const int tid = threadIdx.x;
  const int b   = blockIdx.x / 196;            // 196 blocks (64 px) per image
  const int r0  = (blockIdx.x - b * 196) * 64; // first flat pixel of block
  const float* __restrict__ inb = in + b * CI * HW;

  // ---- stage A-fragments (bf16 weights + bias in K-slot 8) ----
  for (int idx = tid; idx < NP * 32; idx += 512) {
    const int p = idx >> 5, l = idx & 31, q = l >> 4, m = l & 15;
    const int row = p * 16 + m;                // o = p*16 + co
    short8 v = {0, 0, 0, 0, 0, 0, 0, 0};
    if (q == 0) {
      const float* wr = wp + row * CI;
#pragma unroll
      for (int j = 0; j < 8; ++j) v[j] = f2bf(wr[j]);
    } else {
      v[0] = f2bf(bp[row]);                    // K slot 8 = bias
    }
    *(short8*)&sA[p][l][0] = v;
  }
  if (tid < 16) sZ[tid] = 0;
  // ---- stage input neighborhood: flat offsets [r0-113, r0+176] clamped ----
  for (int k = tid; k < CI * 290; k += 512) {
    const int c = k / 290;
    const int i = k - c * 290;
    int gg = r0 - 113 + i;
    gg = (gg < 0) ? 0 : (gg > HW - 1 ? HW - 1 : gg);
    sBuf[k] = inb[c * HW + gg];
  }
  __syncthreads();

  const int wave = tid >> 6;
  const int lane = tid & 63;
  const int g    = wave & 3;                   // pixel group
  const int half = wave >> 2;                  // channel half
  const int ln   = lane & 15;                  // pixel slot = A row m = B col n
  const int quad = lane >> 4;
  const int rwav = r0 + g * 16;
  const int h    = rwav / IMG_W;
  const int wl   = (rwav - h * IMG_W) + ln;    // this lane's pixel column
  const int off  = g * 16 + ln + 113;          // center index into sBuf rows

  // border masks per q = kh*3+kw
  float vm[9];
#pragma unroll
  for (int q = 0; q < 9; ++q) {
    const int kh = q / 3, kw = q % 3;
    const bool ok = ((unsigned)(h + kh - 1) < 112u) &&
                    ((unsigned)(wl + kw - 1) < 112u);
    vm[q] = ok ? 1.f : 0.f;
  }

  // B fragment: quad0 = x[c,n] bf16 (all 8 channels); quad1 = e0 (bias row)
  short8 bf = {0, 0, 0, 0, 0, 0, 0, 0};
#pragma unroll
  for (int j = 0; j < 8; ++j) {
    const short bv = f2bf(sBuf[j * 290 + off]);
    bf[j] = (quad == 0) ? bv : ((quad == 1 && j == 0) ? (short)0x3F80 : (short)0);
  }

  f32x2 acc01 = {0.f, 0.f}, acc23 = {0.f, 0.f};
  f32x2 n01   = {0.f, 0.f}, n23   = {0.f, 0.f};
  const bool qlo = (quad < 2);
  const int  c0  = half * 4;

#pragma unroll 2
  for (int cc = 0; cc < 4; ++cc) {
    const int c = c0 + cc;
    const float* __restrict__ sc = &sBuf[c * 290 + off];
#pragma unroll
    for (int q = 0; q < 9; ++q) {
      const int p = c * 9 + q;
      const short* ap = qlo ? &sA[p][quad * 16 + ln][0] : &sZ[0];
      const short8 af = *(const short8*)ap;
      const float pv = vm[q] * sc[DQ[q]];
      const f32x4 zc = {0.f, 0.f, 0.f, 0.f};
      const f32x4 d = __builtin_amdgcn_mfma_f32_16x16x32_bf16(af, bf, zc, 0, 0, 0);
      f32x2 d01; d01[0] = d[0]; d01[1] = d[1];
      f32x2 d23; d23[0] = d[2]; d23[1] = d[3];
      const f32x2 pv2 = {pv, pv};
      acc01 = __builtin_elementwise_fma(pv2, d01, acc01);
      acc23 = __builtin_elementwise_fma(pv2, d23, acc23);
      n01   = __builtin_elementwise_fma(d01, d01, n01);
      n23   = __builtin_elementwise_fma(d23, d23, n23);
    }
  }

  const float accv[4] = {acc01[0], acc01[1], acc23[0], acc23[1]};
  const float n2v[4]  = {n01[0],   n01[1],   n23[0],   n23[1]};

  // ---- combine halves via LDS (sBuf is dead now), half 0 stores ----
  __syncthreads();
  if (half == 1) {
#pragma unroll
    for (int i = 0; i < 4; ++i) {
      sBuf[i * 256 + g * 64 + lane]       = accv[i];   // conflict-free b32
      sBuf[(i + 4) * 256 + g * 64 + lane] = n2v[i];
    }
  }
  __syncthreads();
  if (half == 0) {
    float* __restrict__ ob = out + (long)b * CO * HW + rwav + ln;
#pragma unroll
    for (int i = 0; i < 4; ++i) {
      const float a2 = accv[i] + sBuf[i * 256 + g * 64 + lane];
      const float s2 = n2v[i] + sBuf[(i + 4) * 256 + g * 64 + lane];
      const int co = quad * 4 + i;                    // C/D row = quad*4+reg
      ob[(long)co * HW] = a2 / (sqrtf(s2) + EPS);
    }
  }
}

extern "C" void kernel_launch(void* const* d_in, const int* in_sizes, int n_in,
                              void* d_out, int out_size, void* d_ws, size_t ws_size,
                              hipStream_t stream) {
  const float* in = (const float*)d_in[0];
  const float* wp = (const float*)d_in[1];
  const float* bp = (const float*)d_in[2];
  float* out = (float*)d_out;

  // 50176 pixels / 64 per block = 784 blocks of 8 waves (p-split pairs)
  coda_mfma<<<dim3(784), dim3(512), 0, stream>>>(in, wp, bp, out);
}

// Round 12
// 73.275 us; speedup vs baseline: 1.0139x; 1.0074x over previous
//
#include <hip/hip_runtime.h>
#include <math.h>

#define IMG_W 112
#define HW    12544          // 112*112
#define CI    8
#define CO    16
#define NP    72             // patch positions
#define EPS   1e-6f

typedef __attribute__((ext_vector_type(4))) _Float16 half4;  // 2 VGPRs
typedef __attribute__((ext_vector_type(4))) float f32x4;

static constexpr int DQ[9] = {-113, -112, -111, -1, 0, 1, 111, 112, 113};

// Round 12 = round 11 with the correct intrinsic spelling:
// __builtin_amdgcn_mfma_f32_16x16x16f16 (legacy K=16 shapes have no
// underscore before the dtype suffix on gfx950).
//  - K=16 holds our 9 slots: c=0..7 + bias at k=8. A-frag = 8B ->
//    ds_read_b64; f16 mantissa > bf16 -> accuracy improves.
//  - Explicit 9-deep pipeline per channel: 9 A-loads -> 9 independent MFMAs
//    -> 9 folds.
//  - All 36 masked patch values preloaded into registers before the loop.
// A-frag layout (16x16x16 f16): lane l: m=l&15 (co), k = (l>>4)*4+j.
// Rows: quad0/1 = w[k=c], quad2 = {bias,0,0,0} (k=8), quad3 = zero row.
__global__ __launch_bounds__(512, 4) void coda_mfma(
    const float* __restrict__ in, const float* __restrict__ wp,
    const float* __restrict__ bp, float* __restrict__ out)
{
  __shared__ half4 sA[NP][48];     // 27648B: [p][quad*16+m], quad<3
  __shared__ float sBuf[CI * 290]; //  9280B: input stage, then partials
  __shared__ half4 sZ[1];          //     8B: zero row for quad3

  const int tid = threadIdx.x;
  const int b   = blockIdx.x / 196;            // 196 blocks (64 px) per image
  const int r0  = (blockIdx.x - b * 196) * 64; // first flat pixel of block
  const float* __restrict__ inb = in + b * CI * HW;

  // ---- stage A-fragments (f16 weights; bias at k=8 in quad2) ----
  for (int idx = tid; idx < NP * 48; idx += 512) {
    const int p = idx / 48, l = idx - p * 48;
    const int quad = l >> 4, m = l & 15;
    const int row = p * 16 + m;                // o = p*16 + co
    half4 v = {(_Float16)0, (_Float16)0, (_Float16)0, (_Float16)0};
    if (quad < 2) {
      const float* wr = wp + row * CI + quad * 4;
#pragma unroll
      for (int j = 0; j < 4; ++j) v[j] = (_Float16)wr[j];
    } else {
      v[0] = (_Float16)bp[row];                // k=8 -> bias
    }
    sA[p][l] = v;
  }
  if (tid == 0) {
    half4 z = {(_Float16)0, (_Float16)0, (_Float16)0, (_Float16)0};
    sZ[0] = z;
  }
  // ---- stage input neighborhood: flat offsets [r0-113, r0+176] clamped ----
  for (int k = tid; k < CI * 290; k += 512) {
    const int c = k / 290;
    const int i = k - c * 290;
    int gg = r0 - 113 + i;
    gg = (gg < 0) ? 0 : (gg > HW - 1 ? HW - 1 : gg);
    sBuf[k] = inb[c * HW + gg];
  }
  __syncthreads();

  const int wave = tid >> 6;
  const int lane = tid & 63;
  const int g    = wave & 3;                   // pixel group
  const int half = wave >> 2;                  // channel half
  const int ln   = lane & 15;                  // pixel slot (B col n, A row m)
  const int quad = lane >> 4;
  const int rwav = r0 + g * 16;
  const int h    = rwav / IMG_W;
  const int wl   = (rwav - h * IMG_W) + ln;    // this lane's pixel column
  const int off  = g * 16 + ln + 113;          // center index into sBuf rows

  // border masks per q = kh*3+kw
  float vm[9];
#pragma unroll
  for (int q = 0; q < 9; ++q) {
    const int kh = q / 3, kw = q % 3;
    const bool ok = ((unsigned)(h + kh - 1) < 112u) &&
                    ((unsigned)(wl + kw - 1) < 112u);
    vm[q] = ok ? 1.f : 0.f;
  }

  const int c0 = half * 4;

  // preload all 36 masked patch values into registers
  float pv[4][9];
#pragma unroll
  for (int cc = 0; cc < 4; ++cc)
#pragma unroll
    for (int q = 0; q < 9; ++q)
      pv[cc][q] = vm[q] * sBuf[(c0 + cc) * 290 + off + DQ[q]];

  // B fragment: quad0 = x[0..3], quad1 = x[4..7], quad2 = {1,0,0,0}, quad3 = 0
  half4 bf = {(_Float16)0, (_Float16)0, (_Float16)0, (_Float16)0};
  if (quad < 2) {
#pragma unroll
    for (int j = 0; j < 4; ++j)
      bf[j] = (_Float16)sBuf[(quad * 4 + j) * 290 + off];
  } else if (quad == 2) {
    bf[0] = (_Float16)1.0f;
  }

  float acc[4] = {0.f, 0.f, 0.f, 0.f};
  float n2[4]  = {0.f, 0.f, 0.f, 0.f};

  const half4* __restrict__ abase = (quad < 3) ? &sA[0][quad * 16 + ln] : &sZ[0];
  const int astep = (quad < 3) ? 48 : 0;       // half4 elements per p

#pragma unroll
  for (int cc = 0; cc < 4; ++cc) {
    const int c = c0 + cc;
    half4 af[9];
#pragma unroll
    for (int q = 0; q < 9; ++q) af[q] = abase[(c * 9 + q) * astep];
    f32x4 d[9];
#pragma unroll
    for (int q = 0; q < 9; ++q) {
      const f32x4 zc = {0.f, 0.f, 0.f, 0.f};
      d[q] = __builtin_amdgcn_mfma_f32_16x16x16f16(af[q], bf, zc, 0, 0, 0);
    }
#pragma unroll
    for (int q = 0; q < 9; ++q) {
      const float p_ = pv[cc][q];
#pragma unroll
      for (int i = 0; i < 4; ++i) {
        acc[i] = fmaf(p_, d[q][i], acc[i]);
        n2[i]  = fmaf(d[q][i], d[q][i], n2[i]);
      }
    }
  }

  // ---- combine halves via LDS (sBuf is dead now), half 0 stores ----
  __syncthreads();
  if (half == 1) {
#pragma unroll
    for (int i = 0; i < 4; ++i) {
      sBuf[i * 256 + g * 64 + lane]       = acc[i];   // conflict-free b32
      sBuf[(i + 4) * 256 + g * 64 + lane] = n2[i];
    }
  }
  __syncthreads();
  if (half == 0) {
    float* __restrict__ ob = out + (long)b * CO * HW + rwav + ln;
#pragma unroll
    for (int i = 0; i < 4; ++i) {
      const float a2 = acc[i] + sBuf[i * 256 + g * 64 + lane];
      const float s2 = n2[i] + sBuf[(i + 4) * 256 + g * 64 + lane];
      const int co = quad * 4 + i;                    // C/D row = quad*4+reg
      ob[(long)co * HW] = a2 / (sqrtf(s2) + EPS);
    }
  }
}

extern "C" void kernel_launch(void* const* d_in, const int* in_sizes, int n_in,
                              void* d_out, int out_size, void* d_ws, size_t ws_size,
                              hipStream_t stream) {
  const float* in = (const float*)d_in[0];
  const float* wp = (const float*)d_in[1];
  const float* bp = (const float*)d_in[2];
  float* out = (float*)d_out;

  // 50176 pixels / 64 per block = 784 blocks of 8 waves (p-split pairs)
  coda_mfma<<<dim3(784), dim3(512), 0, stream>>>(in, wp, bp, out);
}